// Round 6
// baseline (468.647 us; speedup 1.0000x reference)
//
#include <hip/hip_runtime.h>
#include <cstdint>
#include <cstddef>

#define E 32
#define Bsz 64
#define Lsz 2048

typedef float f32x4 __attribute__((ext_vector_type(4)));
typedef __bf16 bf16x8 __attribute__((ext_vector_type(8)));
typedef __bf16 bf16x4 __attribute__((ext_vector_type(4)));
typedef short s16x8 __attribute__((ext_vector_type(8)));
typedef short s16x4 __attribute__((ext_vector_type(4)));
typedef unsigned short u16;

__device__ inline u16 f2bf(float f) {
    union { float f; unsigned u; } x; x.f = f;
    unsigned r = x.u + 0x7FFFu + ((x.u >> 16) & 1u);
    return (u16)(r >> 16);
}

// PV mfma: D = A(16x16) * B(16x16) + C via v_mfma_f32_16x16x16_bf16
__device__ inline f32x4 pv_mfma(bf16x4 a, bf16x4 b, f32x4 c) {
#if __has_builtin(__builtin_amdgcn_mfma_f32_16x16x16_bf16)
    return __builtin_amdgcn_mfma_f32_16x16x16_bf16(a, b, c, 0, 0, 0);
#elif __has_builtin(__builtin_amdgcn_mfma_f32_16x16x16bf16_1k)
    return __builtin_amdgcn_mfma_f32_16x16x16bf16_1k(
        __builtin_bit_cast(s16x4, a), __builtin_bit_cast(s16x4, b), c, 0, 0, 0);
#else
    asm volatile("s_nop 1\n\t"
                 "v_mfma_f32_16x16x16_bf16 %0, %1, %2, %0\n\t"
                 "s_nop 3"
                 : "+v"(c) : "v"(a), "v"(b));
    return c;
#endif
}

// ---------------- PSF mask precompute: M'[i][j] = mask(i,j)/sqrt(E)*log2(e), bf16 ----------------
__global__ __launch_bounds__(256) void mask_kernel(u16* __restrict__ M) {
    int g = blockIdx.x * 256 + threadIdx.x;
    int i = g >> 11, j = g & 2047;
    float z = 0.f;
    #pragma unroll
    for (int x = -10; x <= 10; ++x) z += __expf(-0.125f * (float)(x * x));
    const float scale = 21.0f / 2048.0f;
    float si = fmaxf((i + 0.5f) * scale - 0.5f, 0.f);
    float sj = fmaxf((j + 0.5f) * scale - 0.5f, 0.f);
    int i0 = (int)si; float fi = si - (float)i0;
    int j0 = (int)sj; float fj = sj - (float)j0;
    int i0c = min(i0, 20), i1c = min(i0 + 1, 20);
    int j0c = min(j0, 20), j1c = min(j0 + 1, 20);
    int d00 = abs(i0c - j0c), d01 = abs(i0c - j1c), d10 = abs(i1c - j0c), d11 = abs(i1c - j1c);
    float t00 = __expf(-0.125f * (float)(d00 * d00));
    float t01 = __expf(-0.125f * (float)(d01 * d01));
    float t10 = __expf(-0.125f * (float)(d10 * d10));
    float t11 = __expf(-0.125f * (float)(d11 * d11));
    float m = (1.f - fi) * ((1.f - fj) * t00 + fj * t01)
            + fi * ((1.f - fj) * t10 + fj * t11);
    // * 1/sqrt(32) * log2(e): p = exp(s*m) = exp2(s*m')
    m = (m / z) * 0.17677669529663687f * 1.4426950408889634f;
    M[g] = f2bf(m);
}

// ---------------- QKV projection: x[B][E][L] fp32 -> Q,K [B][L][E] bf16, Vt [B][E][L] bf16 ----------------
__global__ __launch_bounds__(256) void qkv_kernel(const float* __restrict__ x,
        const float* __restrict__ Wqkv, const float* __restrict__ bqkv,
        u16* __restrict__ Q, u16* __restrict__ K, u16* __restrict__ Vt) {
    int g = blockIdx.x * 256 + threadIdx.x;
    int b = g >> 11, l = g & 2047;
    float xr[E];
    #pragma unroll
    for (int c = 0; c < E; ++c) xr[c] = x[((size_t)b * E + c) * Lsz + l];

    #pragma unroll
    for (int part = 0; part < 2; ++part) {
        u16* dst = (part == 0) ? Q : K;
        s16x8 pk[4];
        #pragma unroll
        for (int e = 0; e < E; ++e) {
            int o = part * E + e;
            float acc = bqkv[o];
            #pragma unroll
            for (int c = 0; c < E; ++c) acc += xr[c] * Wqkv[o * E + c];
            pk[e >> 3][e & 7] = (short)f2bf(acc);
        }
        s16x8* dp = (s16x8*)(dst + ((size_t)b * Lsz + l) * E);
        #pragma unroll
        for (int q8 = 0; q8 < 4; ++q8) dp[q8] = pk[q8];
    }
    #pragma unroll
    for (int e = 0; e < E; ++e) {
        int o = 2 * E + e;
        float acc = bqkv[o];
        #pragma unroll
        for (int c = 0; c < E; ++c) acc += xr[c] * Wqkv[o * E + c];
        Vt[((size_t)b * E + e) * Lsz + l] = f2bf(acc);
    }
}

// ---------------- Flash attention v3: fully in-register, no LDS, no barriers ----------------
// Swapped QK^T (S^T = mfma_16x16x32(K,Q)): lane holds q=lrow, j=kgrp*4+r.
// That IS the A-fragment of mfma_f32_16x16x16_bf16 (row=lane&15, k=(lane>>4)*4+e),
// so PV = four 16x16x16 MFMAs with P packed in-register. Zero LDS round-trip.
// grid: B * (L/64) blocks, 256 threads (4 waves x 16 q-rows, waves independent)
__global__ __launch_bounds__(256, 8) void attn_kernel(const u16* __restrict__ Q,
        const u16* __restrict__ Kg, const u16* __restrict__ Vt,
        const u16* __restrict__ M, float* __restrict__ O) {
    int blk = blockIdx.x;
    int b = blk >> 5;        // 32 q-tiles per batch
    int qt = blk & 31;
    int tid = threadIdx.x;
    int wave = tid >> 6, lane = tid & 63;
    int lrow = lane & 15, kgrp = lane >> 4;
    int qbase = qt * 64 + wave * 16;

    const size_t bLE = (size_t)b * Lsz * E;
    // Q as QK B-fragment: lane holds Q[qbase+lrow][kgrp*8 .. +7]
    bf16x8 qf = *(const bf16x8*)(Q + bLE + (size_t)(qbase + lrow) * E + kgrp * 8);

    const u16* kptr  = Kg + bLE + (size_t)lrow * E + kgrp * 8;          // K[j0+lrow][kgrp*8..]
    const u16* v0ptr = Vt + bLE + (size_t)lrow * Lsz + kgrp * 4;        // Vt[lrow][j0+kgrp*4..]
    const u16* v1ptr = Vt + bLE + (size_t)(16 + lrow) * Lsz + kgrp * 4; // Vt[16+lrow][...]
    const u16* mptr  = M + (size_t)(qbase + lrow) * Lsz + kgrp * 4;     // M[q=lrow][j0+kgrp*4..]

    f32x4 o0 = {0.f, 0.f, 0.f, 0.f}, o1 = {0.f, 0.f, 0.f, 0.f};
    float dsum = 0.f;

    for (int j0 = 0; j0 < Lsz; j0 += 32) {
        bf16x8 k0 = *(const bf16x8*)(kptr);             // j-tile 0 (j0..j0+15)
        bf16x8 k1 = *(const bf16x8*)(kptr + 16 * E);    // j-tile 1 (j0+16..j0+31)
        bf16x4 va0 = *(const bf16x4*)(v0ptr);           // V B-frag: tile0, e=lrow
        bf16x4 va1 = *(const bf16x4*)(v0ptr + 16);      // tile1, e=lrow
        bf16x4 vb0 = *(const bf16x4*)(v1ptr);           // tile0, e=16+lrow
        bf16x4 vb1 = *(const bf16x4*)(v1ptr + 16);      // tile1, e=16+lrow
        bf16x4 m0 = *(const bf16x4*)(mptr);             // mask, tile0
        bf16x4 m1 = *(const bf16x4*)(mptr + 16);        // mask, tile1

        f32x4 zc = {0.f, 0.f, 0.f, 0.f};
        f32x4 s0 = __builtin_amdgcn_mfma_f32_16x16x32_bf16(k0, qf, zc, 0, 0, 0);
        f32x4 s1 = __builtin_amdgcn_mfma_f32_16x16x32_bf16(k1, qf, zc, 0, 0, 0);

        bf16x4 pa0, pa1;
        #pragma unroll
        for (int r = 0; r < 4; ++r) {
            float p = exp2f(s0[r] * (float)m0[r]);    // mask carries /sqrt(E)*log2(e)
            dsum += p; pa0[r] = (__bf16)p;
        }
        #pragma unroll
        for (int r = 0; r < 4; ++r) {
            float p = exp2f(s1[r] * (float)m1[r]);
            dsum += p; pa1[r] = (__bf16)p;
        }
        o0 = pv_mfma(pa0, va0, o0);
        o0 = pv_mfma(pa1, va1, o0);
        o1 = pv_mfma(pa0, vb0, o1);
        o1 = pv_mfma(pa1, vb1, o1);

        kptr += 32 * E; v0ptr += 32; v1ptr += 32; mptr += 32;
    }

    // dsum: per-lane partial for q=lrow; reduce across the 4 kgrp groups.
    dsum += __shfl_xor(dsum, 16);
    dsum += __shfl_xor(dsum, 32);
    // PV output: lane holds rows q = kgrp*4+r, cols e = lrow / 16+lrow
    #pragma unroll
    for (int r = 0; r < 4; ++r) {
        float inv = 1.0f / __shfl(dsum, kgrp * 4 + r);
        size_t row = (size_t)(qbase + kgrp * 4 + r);
        O[bLE + row * E + lrow]      = o0[r] * inv;
        O[bLE + row * E + 16 + lrow] = o1[r] * inv;
    }
}

// ---------------- Output projection: O[B][L][E] fp32 -> y[B][E][L] fp32 ----------------
__global__ __launch_bounds__(256) void oproj_kernel(const float* __restrict__ O,
        const float* __restrict__ Wout, const float* __restrict__ bout,
        float* __restrict__ y) {
    int g = blockIdx.x * 256 + threadIdx.x;
    int b = g >> 11, l = g & 2047;
    float orow[E];
    const float* src = O + ((size_t)b * Lsz + l) * E;
    #pragma unroll
    for (int e = 0; e < E; e += 4) {
        f32x4 t = *(const f32x4*)(src + e);
        orow[e] = t[0]; orow[e + 1] = t[1]; orow[e + 2] = t[2]; orow[e + 3] = t[3];
    }
    #pragma unroll
    for (int c = 0; c < E; ++c) {
        float acc = bout[c];
        #pragma unroll
        for (int e = 0; e < E; ++e) acc += orow[e] * Wout[c * E + e];
        y[((size_t)b * E + c) * Lsz + l] = acc;
    }
}

extern "C" void kernel_launch(void* const* d_in, const int* in_sizes, int n_in,
                              void* d_out, int out_size, void* d_ws, size_t ws_size,
                              hipStream_t stream) {
    const float* x    = (const float*)d_in[0];
    const float* Wqkv = (const float*)d_in[1];
    const float* bqkv = (const float*)d_in[2];
    const float* Wout = (const float*)d_in[3];
    const float* bout = (const float*)d_in[4];
    float* y = (float*)d_out;

    char* ws = (char*)d_ws;
    const size_t szQ = (size_t)Bsz * Lsz * E * sizeof(u16);   // 8.39 MB
    const size_t szM = (size_t)Lsz * Lsz * sizeof(u16);       // 8.39 MB
    u16* Q   = (u16*)(ws);
    u16* K   = (u16*)(ws + szQ);
    u16* Vt  = (u16*)(ws + 2 * szQ);
    u16* M   = (u16*)(ws + 3 * szQ);
    float* O = (float*)(ws + 3 * szQ + szM);                  // 16.78 MB fp32

    hipLaunchKernelGGL(mask_kernel, dim3((Lsz * Lsz) / 256), dim3(256), 0, stream, M);
    hipLaunchKernelGGL(qkv_kernel, dim3((Bsz * Lsz) / 256), dim3(256), 0, stream,
                       x, Wqkv, bqkv, Q, K, Vt);
    hipLaunchKernelGGL(attn_kernel, dim3(Bsz * (Lsz / 64)), dim3(256), 0, stream,
                       Q, K, Vt, M, O);
    hipLaunchKernelGGL(oproj_kernel, dim3((Bsz * Lsz) / 256), dim3(256), 0, stream,
                       O, Wout, bout, y);
}

// Round 7
// 448.355 us; speedup vs baseline: 1.0453x; 1.0453x over previous
//
#include <hip/hip_runtime.h>
#include <cstdint>
#include <cstddef>

#define E 32
#define Bsz 64
#define Lsz 2048

typedef float f32x4 __attribute__((ext_vector_type(4)));
typedef __bf16 bf16x8 __attribute__((ext_vector_type(8)));
typedef __bf16 bf16x4 __attribute__((ext_vector_type(4)));
typedef short s16x8 __attribute__((ext_vector_type(8)));
typedef short s16x4 __attribute__((ext_vector_type(4)));
typedef unsigned short u16;

__device__ inline u16 f2bf(float f) {
    union { float f; unsigned u; } x; x.f = f;
    unsigned r = x.u + 0x7FFFu + ((x.u >> 16) & 1u);
    return (u16)(r >> 16);
}

// PV mfma: D = A(16x16) * B(16x16) + C via v_mfma_f32_16x16x16_bf16
__device__ inline f32x4 pv_mfma(bf16x4 a, bf16x4 b, f32x4 c) {
#if __has_builtin(__builtin_amdgcn_mfma_f32_16x16x16_bf16)
    return __builtin_amdgcn_mfma_f32_16x16x16_bf16(a, b, c, 0, 0, 0);
#elif __has_builtin(__builtin_amdgcn_mfma_f32_16x16x16bf16_1k)
    return __builtin_amdgcn_mfma_f32_16x16x16bf16_1k(
        __builtin_bit_cast(s16x4, a), __builtin_bit_cast(s16x4, b), c, 0, 0, 0);
#else
    asm volatile("s_nop 1\n\t"
                 "v_mfma_f32_16x16x16_bf16 %0, %1, %2, %0\n\t"
                 "s_nop 3"
                 : "+v"(c) : "v"(a), "v"(b));
    return c;
#endif
}

// ---------------- T table: T[r][j] = col-lerped Toeplitz row r, * /sqrt(E)*log2(e) ----------------
// mask(i,j) = (1-fi)*T[i0c][j] + fi*T[i1c][j]  (row-lerp done in attn kernel)
__global__ __launch_bounds__(256) void tee_kernel(u16* __restrict__ T) {
    int g = blockIdx.x * 256 + threadIdx.x;     // 21*2048 = 43008 = 168*256 exactly
    int r = g >> 11, j = g & 2047;
    float z = 0.f;
    #pragma unroll
    for (int x = -10; x <= 10; ++x) z += __expf(-0.125f * (float)(x * x));
    const float scale = 21.0f / 2048.0f;
    float sj = fmaxf((j + 0.5f) * scale - 0.5f, 0.f);
    int j0 = (int)sj; float fj = sj - (float)j0;
    int j0c = min(j0, 20), j1c = min(j0 + 1, 20);
    int d0 = abs(r - j0c), d1 = abs(r - j1c);
    float v = (1.f - fj) * __expf(-0.125f * (float)(d0 * d0))
            + fj * __expf(-0.125f * (float)(d1 * d1));
    v = (v / z) * 0.17677669529663687f * 1.4426950408889634f;  // /sqrt(32)*log2(e)
    T[g] = f2bf(v);
}

// ---------------- QKV projection: x[B][E][L] fp32 -> Q,K [B][L][E] bf16, Vt [B][E][L] bf16 ----------------
__global__ __launch_bounds__(256) void qkv_kernel(const float* __restrict__ x,
        const float* __restrict__ Wqkv, const float* __restrict__ bqkv,
        u16* __restrict__ Q, u16* __restrict__ K, u16* __restrict__ Vt) {
    int g = blockIdx.x * 256 + threadIdx.x;
    int b = g >> 11, l = g & 2047;
    float xr[E];
    #pragma unroll
    for (int c = 0; c < E; ++c) xr[c] = x[((size_t)b * E + c) * Lsz + l];

    #pragma unroll
    for (int part = 0; part < 2; ++part) {
        u16* dst = (part == 0) ? Q : K;
        s16x8 pk[4];
        #pragma unroll
        for (int e = 0; e < E; ++e) {
            int o = part * E + e;
            float acc = bqkv[o];
            #pragma unroll
            for (int c = 0; c < E; ++c) acc += xr[c] * Wqkv[o * E + c];
            pk[e >> 3][e & 7] = (short)f2bf(acc);
        }
        s16x8* dp = (s16x8*)(dst + ((size_t)b * Lsz + l) * E);
        #pragma unroll
        for (int q8 = 0; q8 < 4; ++q8) dp[q8] = pk[q8];
    }
    #pragma unroll
    for (int e = 0; e < E; ++e) {
        int o = 2 * E + e;
        float acc = bqkv[o];
        #pragma unroll
        for (int c = 0; c < E; ++c) acc += xr[c] * Wqkv[o * E + c];
        Vt[((size_t)b * E + e) * Lsz + l] = f2bf(acc);
    }
}

// ---------------- Flash attention v4: in-register P, 2-deep prefetch, T-table mask ----------------
// Swapped QK^T (S^T = mfma_16x16x32(K,Q)): lane holds q=lrow, j=kgrp*4+r -> that IS
// the A-fragment of mfma_f32_16x16x16_bf16, so PV needs no LDS and no barriers.
// __launch_bounds__(256,4): 128-VGPR budget so both prefetch stages stay in flight
// (v3's (256,8) -> 28 VGPRs serialized every load = 412us. Occupancy != throughput.)
__global__ __launch_bounds__(256, 4) void attn_kernel(const u16* __restrict__ Q,
        const u16* __restrict__ Kg, const u16* __restrict__ Vt,
        const u16* __restrict__ T, float* __restrict__ O) {
    int blk = blockIdx.x;
    int b = blk >> 5;        // 32 q-tiles per batch
    int qt = blk & 31;
    int tid = threadIdx.x;
    int wave = tid >> 6, lane = tid & 63;
    int lrow = lane & 15, kgrp = lane >> 4;
    int qbase = qt * 64 + wave * 16;

    const size_t bLE = (size_t)b * Lsz * E;
    // Q as QK B-fragment: lane holds Q[qbase+lrow][kgrp*8 .. +7]
    bf16x8 qf = *(const bf16x8*)(Q + bLE + (size_t)(qbase + lrow) * E + kgrp * 8);

    const u16* kptr  = Kg + bLE + (size_t)lrow * E + kgrp * 8;          // K[j+lrow][kgrp*8..]
    const u16* v0ptr = Vt + bLE + (size_t)lrow * Lsz + kgrp * 4;        // Vt[lrow][j+kgrp*4..]
    const u16* v1ptr = Vt + bLE + (size_t)(16 + lrow) * Lsz + kgrp * 4; // Vt[16+lrow][...]

    // mask row-lerp coefficients for this lane's q-row
    int qi = qbase + lrow;
    float si = fmaxf((qi + 0.5f) * (21.0f / 2048.0f) - 0.5f, 0.f);
    int i0 = (int)si; float fi = si - (float)i0;
    const u16* t0p = T + (size_t)min(i0, 20) * Lsz + kgrp * 4;
    const u16* t1p = T + (size_t)min(i0 + 1, 20) * Lsz + kgrp * 4;

    f32x4 o0 = {0.f, 0.f, 0.f, 0.f}, o1 = {0.f, 0.f, 0.f, 0.f};
    float dsum = 0.f;

#define LOADS(off, kk0, kk1, vv0, vv1, vv2, vv3, ta0, ta1, tb0, tb1) do { \
    kk0 = *(const bf16x8*)(kptr + (size_t)(off) * E);        \
    kk1 = *(const bf16x8*)(kptr + (size_t)((off) + 16) * E); \
    vv0 = *(const bf16x4*)(v0ptr + (off));                   \
    vv1 = *(const bf16x4*)(v0ptr + (off) + 16);              \
    vv2 = *(const bf16x4*)(v1ptr + (off));                   \
    vv3 = *(const bf16x4*)(v1ptr + (off) + 16);              \
    ta0 = *(const bf16x4*)(t0p + (off));                     \
    ta1 = *(const bf16x4*)(t0p + (off) + 16);                \
    tb0 = *(const bf16x4*)(t1p + (off));                     \
    tb1 = *(const bf16x4*)(t1p + (off) + 16);                \
} while (0)

#define COMPUTE(kk0, kk1, vv0, vv1, vv2, vv3, ta0, ta1, tb0, tb1) do { \
    f32x4 zc = {0.f, 0.f, 0.f, 0.f}; \
    f32x4 s0 = __builtin_amdgcn_mfma_f32_16x16x32_bf16(kk0, qf, zc, 0, 0, 0); \
    f32x4 s1 = __builtin_amdgcn_mfma_f32_16x16x32_bf16(kk1, qf, zc, 0, 0, 0); \
    bf16x4 pa0, pa1; \
    _Pragma("unroll") \
    for (int r = 0; r < 4; ++r) { \
        float ta = (float)ta0[r], tb = (float)tb0[r]; \
        float p = exp2f(s0[r] * (ta + fi * (tb - ta))); \
        dsum += p; pa0[r] = (__bf16)p; \
    } \
    _Pragma("unroll") \
    for (int r = 0; r < 4; ++r) { \
        float ta = (float)ta1[r], tb = (float)tb1[r]; \
        float p = exp2f(s1[r] * (ta + fi * (tb - ta))); \
        dsum += p; pa1[r] = (__bf16)p; \
    } \
    o0 = pv_mfma(pa0, vv0, o0); \
    o0 = pv_mfma(pa1, vv1, o0); \
    o1 = pv_mfma(pa0, vv2, o1); \
    o1 = pv_mfma(pa1, vv3, o1); \
} while (0)

    bf16x8 kA0, kA1, kB0, kB1;
    bf16x4 vA0, vA1, vA2, vA3, vB0, vB1, vB2, vB3;
    bf16x4 tA0, tA1, tA2, tA3, tB0, tB1, tB2, tB3;

    LOADS(0, kA0, kA1, vA0, vA1, vA2, vA3, tA0, tA1, tA2, tA3);
    for (int j0 = 0; j0 < Lsz; j0 += 64) {
        LOADS(j0 + 32, kB0, kB1, vB0, vB1, vB2, vB3, tB0, tB1, tB2, tB3);
        COMPUTE(kA0, kA1, vA0, vA1, vA2, vA3, tA0, tA1, tA2, tA3);
        // final-iteration overread (off=2048) lands in adjacent allocated ws
        // regions (K->Vt->T->O); values never used.
        LOADS(j0 + 64, kA0, kA1, vA0, vA1, vA2, vA3, tA0, tA1, tA2, tA3);
        COMPUTE(kB0, kB1, vB0, vB1, vB2, vB3, tB0, tB1, tB2, tB3);
    }
#undef LOADS
#undef COMPUTE

    // dsum: per-lane partial for q=lrow; reduce across the 4 kgrp groups.
    dsum += __shfl_xor(dsum, 16);
    dsum += __shfl_xor(dsum, 32);
    // PV output: lane holds rows q = kgrp*4+r, cols e = lrow / 16+lrow
    #pragma unroll
    for (int r = 0; r < 4; ++r) {
        float inv = 1.0f / __shfl(dsum, kgrp * 4 + r);
        size_t row = (size_t)(qbase + kgrp * 4 + r);
        O[bLE + row * E + lrow]      = o0[r] * inv;
        O[bLE + row * E + 16 + lrow] = o1[r] * inv;
    }
}

// ---------------- Output projection: O[B][L][E] fp32 -> y[B][E][L] fp32 ----------------
__global__ __launch_bounds__(256) void oproj_kernel(const float* __restrict__ O,
        const float* __restrict__ Wout, const float* __restrict__ bout,
        float* __restrict__ y) {
    int g = blockIdx.x * 256 + threadIdx.x;
    int b = g >> 11, l = g & 2047;
    float orow[E];
    const float* src = O + ((size_t)b * Lsz + l) * E;
    #pragma unroll
    for (int e = 0; e < E; e += 4) {
        f32x4 t = *(const f32x4*)(src + e);
        orow[e] = t[0]; orow[e + 1] = t[1]; orow[e + 2] = t[2]; orow[e + 3] = t[3];
    }
    #pragma unroll
    for (int c = 0; c < E; ++c) {
        float acc = bout[c];
        #pragma unroll
        for (int e = 0; e < E; ++e) acc += orow[e] * Wout[c * E + e];
        y[((size_t)b * E + c) * Lsz + l] = acc;
    }
}

extern "C" void kernel_launch(void* const* d_in, const int* in_sizes, int n_in,
                              void* d_out, int out_size, void* d_ws, size_t ws_size,
                              hipStream_t stream) {
    const float* x    = (const float*)d_in[0];
    const float* Wqkv = (const float*)d_in[1];
    const float* bqkv = (const float*)d_in[2];
    const float* Wout = (const float*)d_in[3];
    const float* bout = (const float*)d_in[4];
    float* y = (float*)d_out;

    char* ws = (char*)d_ws;
    const size_t szQ = (size_t)Bsz * Lsz * E * sizeof(u16);   // 8.39 MB
    const size_t szT = (size_t)21 * Lsz * sizeof(u16);        // 86 KB
    u16* Q   = (u16*)(ws);
    u16* K   = (u16*)(ws + szQ);
    u16* Vt  = (u16*)(ws + 2 * szQ);
    u16* T   = (u16*)(ws + 3 * szQ);
    float* O = (float*)(ws + 3 * szQ + szT);                  // 16.78 MB fp32

    hipLaunchKernelGGL(tee_kernel, dim3((21 * Lsz) / 256), dim3(256), 0, stream, T);
    hipLaunchKernelGGL(qkv_kernel, dim3((Bsz * Lsz) / 256), dim3(256), 0, stream,
                       x, Wqkv, bqkv, Q, K, Vt);
    hipLaunchKernelGGL(attn_kernel, dim3(Bsz * (Lsz / 64)), dim3(256), 0, stream,
                       Q, K, Vt, T, O);
    hipLaunchKernelGGL(oproj_kernel, dim3((Bsz * Lsz) / 256), dim3(256), 0, stream,
                       O, Wout, bout, y);
}

// Round 8
// 189.876 us; speedup vs baseline: 2.4682x; 2.3613x over previous
//
#include <hip/hip_runtime.h>
#include <cstdint>
#include <cstddef>

#define E 32
#define Bsz 64
#define Lsz 2048
#define NCHUNK (Lsz / 64)

typedef float f32x4 __attribute__((ext_vector_type(4)));
typedef __bf16 bf16x8 __attribute__((ext_vector_type(8)));
typedef __bf16 bf16x4 __attribute__((ext_vector_type(4)));
typedef short s16x8 __attribute__((ext_vector_type(8)));
typedef short s16x4 __attribute__((ext_vector_type(4)));
typedef unsigned short u16;

typedef __attribute__((address_space(3))) unsigned int as3_u32;
typedef __attribute__((address_space(1))) const unsigned int as1_u32;

__device__ inline u16 f2bf(float f) {
    union { float f; unsigned u; } x; x.f = f;
    unsigned r = x.u + 0x7FFFu + ((x.u >> 16) & 1u);
    return (u16)(r >> 16);
}

// async global -> LDS, 16 B per lane; l must be wave-uniform (HW adds lane*16)
__device__ inline void glds(const void* g, void* l) {
    __builtin_amdgcn_global_load_lds((as1_u32*)g, (as3_u32*)l, 16, 0, 0);
}

// hardware transpose read: lane l elem r <- lds[base + (l&15)*2 + r*32 + (l>>4)*128]
#define TRR(dst, areg, imm) \
    asm volatile("ds_read_b64_tr_b16 %0, %1 offset:" #imm : "=v"(dst) : "v"(areg))

// PV mfma: D = A(16x16) * B(16x16) + C
__device__ inline f32x4 pv_mfma(bf16x4 a, bf16x4 b, f32x4 c) {
#if __has_builtin(__builtin_amdgcn_mfma_f32_16x16x16_bf16)
    return __builtin_amdgcn_mfma_f32_16x16x16_bf16(a, b, c, 0, 0, 0);
#elif __has_builtin(__builtin_amdgcn_mfma_f32_16x16x16bf16_1k)
    return __builtin_amdgcn_mfma_f32_16x16x16bf16_1k(
        __builtin_bit_cast(s16x4, a), __builtin_bit_cast(s16x4, b), c, 0, 0, 0);
#else
    asm volatile("s_nop 1\n\t"
                 "v_mfma_f32_16x16x16_bf16 %0, %1, %2, %0\n\t"
                 "s_nop 3"
                 : "+v"(c) : "v"(a), "v"(b));
    return c;
#endif
}

// ---------------- T table: T[r][j] = col-lerped Toeplitz row r, * /sqrt(E)*log2(e) ----------------
__global__ __launch_bounds__(256) void tee_kernel(u16* __restrict__ T) {
    int g = blockIdx.x * 256 + threadIdx.x;     // 21*2048 = 168*256
    int r = g >> 11, j = g & 2047;
    float z = 0.f;
    #pragma unroll
    for (int x = -10; x <= 10; ++x) z += __expf(-0.125f * (float)(x * x));
    const float scale = 21.0f / 2048.0f;
    float sj = fmaxf((j + 0.5f) * scale - 0.5f, 0.f);
    int j0 = (int)sj; float fj = sj - (float)j0;
    int j0c = min(j0, 20), j1c = min(j0 + 1, 20);
    int d0 = abs(r - j0c), d1 = abs(r - j1c);
    float v = (1.f - fj) * __expf(-0.125f * (float)(d0 * d0))
            + fj * __expf(-0.125f * (float)(d1 * d1));
    v = (v / z) * 0.17677669529663687f * 1.4426950408889634f;  // /sqrt(32)*log2(e)
    T[g] = f2bf(v);
}

// ---------------- QKV: x[B][E][L] f32 -> Q,K [B][L][E] bf16; V chunked tr-layout ----------------
// Vc[b][jc=l>>6][eh=e>>4][j=l&63][e&15]  (matches attn's LDS image; 4-KB chunks)
__global__ __launch_bounds__(256) void qkv_kernel(const float* __restrict__ x,
        const float* __restrict__ Wqkv, const float* __restrict__ bqkv,
        u16* __restrict__ Q, u16* __restrict__ K, u16* __restrict__ Vc) {
    int g = blockIdx.x * 256 + threadIdx.x;
    int b = g >> 11, l = g & 2047;
    float xr[E];
    #pragma unroll
    for (int c = 0; c < E; ++c) xr[c] = x[((size_t)b * E + c) * Lsz + l];

    #pragma unroll
    for (int part = 0; part < 2; ++part) {
        u16* dst = (part == 0) ? Q : K;
        s16x8 pk[4];
        #pragma unroll
        for (int e = 0; e < E; ++e) {
            int o = part * E + e;
            float acc = bqkv[o];
            #pragma unroll
            for (int c = 0; c < E; ++c) acc += xr[c] * Wqkv[o * E + c];
            pk[e >> 3][e & 7] = (short)f2bf(acc);
        }
        s16x8* dp = (s16x8*)(dst + ((size_t)b * Lsz + l) * E);
        #pragma unroll
        for (int q8 = 0; q8 < 4; ++q8) dp[q8] = pk[q8];
    }
    s16x8 pv[4];
    #pragma unroll
    for (int e = 0; e < E; ++e) {
        int o = 2 * E + e;
        float acc = bqkv[o];
        #pragma unroll
        for (int c = 0; c < E; ++c) acc += xr[c] * Wqkv[o * E + c];
        pv[e >> 3][e & 7] = (short)f2bf(acc);
    }
    u16* vd = Vc + ((size_t)b * 32 + (l >> 6)) * 2048 + (size_t)(l & 63) * 16;
    *(s16x8*)(vd)            = pv[0];   // eh=0, e 0..7
    *(s16x8*)(vd + 8)        = pv[1];   // eh=0, e 8..15
    *(s16x8*)(vd + 1024)     = pv[2];   // eh=1, e 16..23
    *(s16x8*)(vd + 1024 + 8) = pv[3];   // eh=1, e 24..31
}

// ---------------- Flash attention v5: LDS-staged chunks, tr-read V, in-register P ----------------
// 1024 blocks (B x L/128), 4 waves x 32 q-rows. j-chunk 64, double-buffered LDS.
__global__ __launch_bounds__(256, 4) void attn_kernel(const u16* __restrict__ Q,
        const u16* __restrict__ Kg, const u16* __restrict__ Vc,
        const u16* __restrict__ T, float* __restrict__ O) {
    int blk = blockIdx.x;
    int b = blk >> 4;
    int qblk = blk & 15;
    int tid = threadIdx.x;
    int lane = tid & 63;
    int lrow = lane & 15, kgrp = lane >> 4;
    int qbase = qblk * 128 + (tid >> 6) * 32;

    __shared__ __align__(1024) u16 K_lds[2][64][32];      // 8 KB, XOR-swizzled slots
    __shared__ __align__(2048) u16 V_lds[2][2][64][16];   // 8 KB, tr-read layout

    const size_t bLE = (size_t)b * Lsz * E;
    bf16x8 qf0 = *(const bf16x8*)(Q + bLE + (size_t)(qbase + lrow) * E + kgrp * 8);
    bf16x8 qf1 = *(const bf16x8*)(Q + bLE + (size_t)(qbase + 16 + lrow) * E + kgrp * 8);

    // mask row-lerp setup per q-tile (verified in v4)
    int qi0 = qbase + lrow, qi1 = qbase + 16 + lrow;
    float si0 = fmaxf((qi0 + 0.5f) * (21.0f / 2048.0f) - 0.5f, 0.f);
    float si1 = fmaxf((qi1 + 0.5f) * (21.0f / 2048.0f) - 0.5f, 0.f);
    int i00 = (int)si0; float fi0 = si0 - (float)i00;
    int i01 = (int)si1; float fi1 = si1 - (float)i01;
    const u16* t0p0 = T + (size_t)min(i00, 20) * Lsz + kgrp * 4;
    const u16* t1p0 = T + (size_t)min(i00 + 1, 20) * Lsz + kgrp * 4;
    const u16* t0p1 = T + (size_t)min(i01, 20) * Lsz + kgrp * 4;
    const u16* t1p1 = T + (size_t)min(i01 + 1, 20) * Lsz + kgrp * 4;

    // staging addresses. K source pre-swizzled so LDS slot s holds K[j][slot s^(j&3)]
    const char* kcbase = (const char*)(Kg + bLE);
    const char* vcbase = (const char*)(Vc + bLE);
    int j_of_tid = tid >> 2;
    int ksrc_off = j_of_tid * 64 + (((tid & 3) ^ (j_of_tid & 3)) << 4);
    int vsrc_off = tid * 16;
    u16* kdst = &K_lds[0][(tid >> 6) * 16][0];        // wave-uniform
    u16* vdst = &V_lds[0][0][0][0] + (tid >> 6) * 512;
    // read-side: swizzled K slot (half units), loop-invariant
    int kslot = (kgrp ^ (lrow & 3)) * 8;
    unsigned vtr0 = (unsigned)(uintptr_t)(__attribute__((address_space(3))) u16*)(&V_lds[0][0][0][0])
                  + (unsigned)(lane * 8);

#define STAGE(bufn, jc_) do { \
    glds(kcbase + (size_t)(jc_) * 4096 + ksrc_off, kdst + (bufn) * 2048); \
    glds(vcbase + (size_t)(jc_) * 4096 + vsrc_off, vdst + (bufn) * 2048); \
} while (0)

    f32x4 o00 = {0,0,0,0}, o01 = {0,0,0,0}, o10 = {0,0,0,0}, o11 = {0,0,0,0};
    f32x4 dn0 = {0,0,0,0}, dn1 = {0,0,0,0};
    bf16x4 ones = {(__bf16)1.0f, (__bf16)1.0f, (__bf16)1.0f, (__bf16)1.0f};

#define JT(jt, vr0, vr1) do { \
    bf16x8 kf = *(const bf16x8*)&K_lds[buf][(jt) * 16 + lrow][kslot]; \
    f32x4 zc = {0,0,0,0}; \
    f32x4 s0 = __builtin_amdgcn_mfma_f32_16x16x32_bf16(kf, qf0, zc, 0, 0, 0); \
    f32x4 s1 = __builtin_amdgcn_mfma_f32_16x16x32_bf16(kf, qf1, zc, 0, 0, 0); \
    bf16x4 ta0 = *(const bf16x4*)(t0p0 + jco + (jt) * 16); \
    bf16x4 tb0 = *(const bf16x4*)(t1p0 + jco + (jt) * 16); \
    bf16x4 ta1 = *(const bf16x4*)(t0p1 + jco + (jt) * 16); \
    bf16x4 tb1 = *(const bf16x4*)(t1p1 + jco + (jt) * 16); \
    bf16x4 pa0, pa1; \
    _Pragma("unroll") for (int r = 0; r < 4; ++r) { \
        float ta = (float)ta0[r], tb = (float)tb0[r]; \
        pa0[r] = (__bf16)exp2f(s0[r] * (ta + fi0 * (tb - ta))); \
    } \
    _Pragma("unroll") for (int r = 0; r < 4; ++r) { \
        float ta = (float)ta1[r], tb = (float)tb1[r]; \
        pa1[r] = (__bf16)exp2f(s1[r] * (ta + fi1 * (tb - ta))); \
    } \
    bf16x4 vf0 = __builtin_bit_cast(bf16x4, vr0); \
    bf16x4 vf1 = __builtin_bit_cast(bf16x4, vr1); \
    o00 = pv_mfma(pa0, vf0, o00); \
    o01 = pv_mfma(pa0, vf1, o01); \
    o10 = pv_mfma(pa1, vf0, o10); \
    o11 = pv_mfma(pa1, vf1, o11); \
    dn0 = pv_mfma(pa0, ones, dn0); \
    dn1 = pv_mfma(pa1, ones, dn1); \
} while (0)

    int buf = 0;
    STAGE(0, 0);
    __syncthreads();
    #pragma unroll 1
    for (int jc = 0; jc < NCHUNK; ++jc) {
        if (jc + 1 < NCHUNK) STAGE(buf ^ 1, jc + 1);   // issue next chunk (other buffer)
        unsigned av = vtr0 + (buf ? 4096u : 0u);
        s16x4 v00r, v01r, v10r, v11r, v20r, v21r, v30r, v31r;
        TRR(v00r, av, 0);    TRR(v01r, av, 2048);      // jt0: eh0, eh1
        TRR(v10r, av, 512);  TRR(v11r, av, 2560);      // jt1
        TRR(v20r, av, 1024); TRR(v21r, av, 3072);      // jt2
        TRR(v30r, av, 1536); TRR(v31r, av, 3584);      // jt3
        asm volatile("s_waitcnt lgkmcnt(0)" ::: "memory");
        __builtin_amdgcn_sched_barrier(0);
        const int jco = jc * 64;
        JT(0, v00r, v01r);
        JT(1, v10r, v11r);
        JT(2, v20r, v21r);
        JT(3, v30r, v31r);
        __syncthreads();   // drains stage vmcnt; all waves done reading buf
        buf ^= 1;
    }
#undef JT
#undef STAGE

    // epilogue: denom came from ones-MFMA in matching layout -> no shuffles
    #pragma unroll
    for (int r = 0; r < 4; ++r) {
        float inv0 = 1.0f / dn0[r];
        float inv1 = 1.0f / dn1[r];
        size_t r0 = (size_t)(qbase + kgrp * 4 + r);
        size_t r1 = (size_t)(qbase + 16 + kgrp * 4 + r);
        O[bLE + r0 * E + lrow]      = o00[r] * inv0;
        O[bLE + r0 * E + 16 + lrow] = o01[r] * inv0;
        O[bLE + r1 * E + lrow]      = o10[r] * inv1;
        O[bLE + r1 * E + 16 + lrow] = o11[r] * inv1;
    }
}

// ---------------- Output projection: O[B][L][E] f32 -> y[B][E][L] f32 ----------------
__global__ __launch_bounds__(256) void oproj_kernel(const float* __restrict__ O,
        const float* __restrict__ Wout, const float* __restrict__ bout,
        float* __restrict__ y) {
    int g = blockIdx.x * 256 + threadIdx.x;
    int b = g >> 11, l = g & 2047;
    float orow[E];
    const float* src = O + ((size_t)b * Lsz + l) * E;
    #pragma unroll
    for (int e = 0; e < E; e += 4) {
        f32x4 t = *(const f32x4*)(src + e);
        orow[e] = t[0]; orow[e + 1] = t[1]; orow[e + 2] = t[2]; orow[e + 3] = t[3];
    }
    #pragma unroll
    for (int c = 0; c < E; ++c) {
        float acc = bout[c];
        #pragma unroll
        for (int e = 0; e < E; ++e) acc += orow[e] * Wout[c * E + e];
        y[((size_t)b * E + c) * Lsz + l] = acc;
    }
}

extern "C" void kernel_launch(void* const* d_in, const int* in_sizes, int n_in,
                              void* d_out, int out_size, void* d_ws, size_t ws_size,
                              hipStream_t stream) {
    const float* x    = (const float*)d_in[0];
    const float* Wqkv = (const float*)d_in[1];
    const float* bqkv = (const float*)d_in[2];
    const float* Wout = (const float*)d_in[3];
    const float* bout = (const float*)d_in[4];
    float* y = (float*)d_out;

    char* ws = (char*)d_ws;
    const size_t szQ = (size_t)Bsz * Lsz * E * sizeof(u16);   // 8.39 MB
    const size_t szT = (size_t)21 * Lsz * sizeof(u16);        // 86 KB
    u16* Q   = (u16*)(ws);
    u16* K   = (u16*)(ws + szQ);
    u16* Vc  = (u16*)(ws + 2 * szQ);
    u16* T   = (u16*)(ws + 3 * szQ);
    float* O = (float*)(ws + 3 * szQ + szT);                  // 16.78 MB f32

    hipLaunchKernelGGL(tee_kernel, dim3((21 * Lsz) / 256), dim3(256), 0, stream, T);
    hipLaunchKernelGGL(qkv_kernel, dim3((Bsz * Lsz) / 256), dim3(256), 0, stream,
                       x, Wqkv, bqkv, Q, K, Vc);
    hipLaunchKernelGGL(attn_kernel, dim3(Bsz * (Lsz / 128)), dim3(256), 0, stream,
                       Q, K, Vc, T, O);
    hipLaunchKernelGGL(oproj_kernel, dim3((Bsz * Lsz) / 256), dim3(256), 0, stream,
                       O, Wout, bout, y);
}